// Round 4
// baseline (427.780 us; speedup 1.0000x reference)
//
#include <hip/hip_runtime.h>
#include <hip/hip_bf16.h>

#define NN 100000
#define NE 1600000
#define FIN 512
#define FH 32
#define FC 16
#define SCAN_B 1024
#define NBLK ((NN + SCAN_B - 1) / SCAN_B)  // 98
#define KHALF 256                          // split-K half size
#define GB1 ((NN + 255) / 256)             // 391 node-blocks

// ---------------- zero cnt (replaces slow rocclr fillBuffer) ----------------

__global__ void k_zero(int4* __restrict__ p, int n4) {
    int i = blockIdx.x * blockDim.x + threadIdx.x;
    if (i < n4) p[i] = make_int4(0, 0, 0, 0);
}

// ---------------- degree histogram: 4 edges/thread for MLP ----------------

__global__ void k_count(const int* __restrict__ col, int* __restrict__ cnt) {
    int i = blockIdx.x * blockDim.x + threadIdx.x;  // edge-quad index
    if (i >= NE / 4) return;
    int4 c4 = ((const int4*)col)[i];
    atomicAdd(&cnt[c4.x], 1);
    atomicAdd(&cnt[c4.y], 1);
    atomicAdd(&cnt[c4.z], 1);
    atomicAdd(&cnt[c4.w], 1);
}

__global__ void k_dis(const int* __restrict__ cnt, float* __restrict__ dis) {
    int n = blockIdx.x * blockDim.x + threadIdx.x;
    if (n < NN) dis[n] = rsqrtf((float)cnt[n] + 1.0f);  // +1 self-loop
}

// ---------------- exclusive prefix scan of cnt -> off, cur ----------------

__global__ __launch_bounds__(SCAN_B) void k_blocksum(const int* __restrict__ cnt,
                                                     int* __restrict__ part) {
    __shared__ int s[SCAN_B];
    int i = blockIdx.x * SCAN_B + threadIdx.x;
    s[threadIdx.x] = (i < NN) ? cnt[i] : 0;
    __syncthreads();
    for (int st = SCAN_B / 2; st > 0; st >>= 1) {
        if (threadIdx.x < st) s[threadIdx.x] += s[threadIdx.x + st];
        __syncthreads();
    }
    if (threadIdx.x == 0) part[blockIdx.x] = s[0];
}

__global__ __launch_bounds__(128) void k_scanpart(int* __restrict__ part) {
    __shared__ int s[128];
    int t = threadIdx.x;
    int v = (t < NBLK) ? part[t] : 0;
    s[t] = v;
    __syncthreads();
    for (int st = 1; st < 128; st <<= 1) {
        int a = (t >= st) ? s[t - st] : 0;
        __syncthreads();
        s[t] += a;
        __syncthreads();
    }
    if (t < NBLK) part[t] = s[t] - v;  // exclusive
}

__global__ __launch_bounds__(SCAN_B) void k_scanblock(const int* __restrict__ cnt,
                                                      const int* __restrict__ part,
                                                      int* __restrict__ off,
                                                      int* __restrict__ cur) {
    __shared__ int s[SCAN_B];
    int i = blockIdx.x * SCAN_B + threadIdx.x;
    int v = (i < NN) ? cnt[i] : 0;
    s[threadIdx.x] = v;
    __syncthreads();
    for (int st = 1; st < SCAN_B; st <<= 1) {
        int add = (threadIdx.x >= st) ? s[threadIdx.x - st] : 0;
        __syncthreads();
        s[threadIdx.x] += add;
        __syncthreads();
    }
    if (i < NN) {
        int o = part[blockIdx.x] + s[threadIdx.x] - v;  // exclusive
        off[i] = o;
        cur[i] = o;  // mutable copy for k_fill
    }
    if (i == NN - 1) off[NN] = part[blockIdx.x] + s[threadIdx.x];
}

// ---------------- CSR fill: 4 edges/thread for MLP ----------------

__global__ void k_fill(const int* __restrict__ row, const int* __restrict__ col,
                       const float* __restrict__ dis,
                       int* __restrict__ cur, int* __restrict__ src,
                       float* __restrict__ wgt) {
    int i = blockIdx.x * blockDim.x + threadIdx.x;  // edge-quad index
    if (i >= NE / 4) return;
    int4 r4 = ((const int4*)row)[i];
    int4 c4 = ((const int4*)col)[i];
    int rr[4] = {r4.x, r4.y, r4.z, r4.w};
    int cc[4] = {c4.x, c4.y, c4.z, c4.w};
    float dr[4], dc[4];
    int p[4];
#pragma unroll
    for (int u = 0; u < 4; ++u) dr[u] = dis[rr[u]];
#pragma unroll
    for (int u = 0; u < 4; ++u) dc[u] = dis[cc[u]];
#pragma unroll
    for (int u = 0; u < 4; ++u) p[u] = atomicAdd(&cur[cc[u]], 1);
#pragma unroll
    for (int u = 0; u < 4; ++u) {
        src[p[u]] = rr[u];
        wgt[p[u]] = dr[u] * dc[u];
    }
}

// ---------------- GEMM1 split-K: 8-deep float4 ILP ----------------

__global__ __launch_bounds__(256) void k_gemm1s(const float* __restrict__ x,
                                                const float* __restrict__ W1,
                                                float* __restrict__ p0,
                                                float* __restrict__ p1) {
    int half = blockIdx.x & 1;
    int nb = blockIdx.x >> 1;
    int ks = half ? KHALF : 0;
    float* dst = half ? p1 : p0;

    __shared__ float Wl[KHALF * FH];  // 32 KB
    const float4* wsrc = (const float4*)(W1 + (size_t)ks * FH);
    for (int i = threadIdx.x; i < KHALF * FH / 4; i += 256)
        ((float4*)Wl)[i] = wsrc[i];
    __syncthreads();

    int n = nb * 256 + threadIdx.x;
    if (n >= NN) return;

    float acc[FH];
#pragma unroll
    for (int j = 0; j < FH; ++j) acc[j] = 0.0f;

    const float4* xr = (const float4*)(x + (size_t)n * FIN + ks);
    for (int kg = 0; kg < KHALF / 4; kg += 8) {
        float4 xv[8];
#pragma unroll
        for (int u = 0; u < 8; ++u) xv[u] = xr[kg + u];
#pragma unroll
        for (int u = 0; u < 8; ++u) {
            const float* xs = (const float*)&xv[u];
#pragma unroll
            for (int kk = 0; kk < 4; ++kk) {
                float xk = xs[kk];
                const float* wrow = &Wl[((kg + u) * 4 + kk) * FH];
#pragma unroll
                for (int j = 0; j < FH; ++j) acc[j] += xk * wrow[j];
            }
        }
    }
    float4* outp = (float4*)(dst + (size_t)n * FH);
#pragma unroll
    for (int j = 0; j < FH / 4; ++j)
        outp[j] = make_float4(acc[4 * j], acc[4 * j + 1], acc[4 * j + 2], acc[4 * j + 3]);
}

// ---------------- combine split-K partials: h1 += p1 ----------------

__global__ void k_comb(float* __restrict__ h1, const float* __restrict__ p1) {
    int i = blockIdx.x * blockDim.x + threadIdx.x;
    if (i < NN * FH / 4) {
        float4 a = ((const float4*)h1)[i];
        float4 b = ((const float4*)p1)[i];
        ((float4*)h1)[i] = make_float4(a.x + b.x, a.y + b.y, a.z + b.z, a.w + b.w);
    }
}

// ---------------- gather layer1 + self-loop + bias + relu -> hr ----------------

__global__ __launch_bounds__(256) void k_gather1(const int* __restrict__ off,
                                                 const int* __restrict__ src,
                                                 const float* __restrict__ wgt,
                                                 const float* __restrict__ h1,
                                                 const float* __restrict__ dis,
                                                 const float* __restrict__ b1,
                                                 float* __restrict__ hr) {
    int g = blockIdx.x * (256 / FH) + threadIdx.x / FH;
    int f = threadIdx.x & (FH - 1);
    if (g >= NN) return;
    int s0 = off[g], s1 = off[g + 1];
    float acc = 0.0f;
    for (int i = s0; i < s1; ++i) {
        int r = src[i];
        acc += h1[(size_t)r * FH + f] * wgt[i];
    }
    float d2 = dis[g] * dis[g];
    float v = acc + h1[(size_t)g * FH + f] * d2 + b1[f];
    hr[(size_t)g * FH + f] = v > 0.0f ? v : 0.0f;
}

// ---------------- GEMM2: h2 = hr @ W2 (32 -> 16) ----------------

__global__ __launch_bounds__(256) void k_gemm2(const float* __restrict__ hr,
                                               const float* __restrict__ W2,
                                               float* __restrict__ h2) {
    __shared__ float Wl[FH * FC];  // 2 KB
    for (int i = threadIdx.x; i < FH * FC; i += 256) Wl[i] = W2[i];
    __syncthreads();
    int n = blockIdx.x * blockDim.x + threadIdx.x;
    if (n >= NN) return;
    float h[FH];
    const float4* hp = (const float4*)(hr + (size_t)n * FH);
#pragma unroll
    for (int j = 0; j < FH / 4; ++j) {
        float4 t = hp[j];
        h[4 * j] = t.x; h[4 * j + 1] = t.y; h[4 * j + 2] = t.z; h[4 * j + 3] = t.w;
    }
#pragma unroll
    for (int j = 0; j < FC; ++j) {
        float s = 0.0f;
#pragma unroll
        for (int k = 0; k < FH; ++k) s += h[k] * Wl[k * FC + j];
        h2[(size_t)n * FC + j] = s;
    }
}

// ---------------- gather layer2 + self-loop + bias + log_softmax -> out ----------------

__global__ __launch_bounds__(256) void k_gather2(const int* __restrict__ off,
                                                 const int* __restrict__ src,
                                                 const float* __restrict__ wgt,
                                                 const float* __restrict__ h2,
                                                 const float* __restrict__ dis,
                                                 const float* __restrict__ b2,
                                                 float* __restrict__ out) {
    int g = blockIdx.x * (256 / FC) + threadIdx.x / FC;
    int f = threadIdx.x & (FC - 1);
    if (g >= NN) return;
    int s0 = off[g], s1 = off[g + 1];
    float acc = 0.0f;
    for (int i = s0; i < s1; ++i) {
        int r = src[i];
        acc += h2[(size_t)r * FC + f] * wgt[i];
    }
    float d2 = dis[g] * dis[g];
    float v = acc + h2[(size_t)g * FC + f] * d2 + b2[f];
    float m = v;
#pragma unroll
    for (int o = 1; o < FC; o <<= 1) m = fmaxf(m, __shfl_xor(m, o, FC));
    float e = __expf(v - m);
    float s = e;
#pragma unroll
    for (int o = 1; o < FC; o <<= 1) s += __shfl_xor(s, o, FC);
    out[(size_t)g * FC + f] = v - m - logf(s);
}

extern "C" void kernel_launch(void* const* d_in, const int* in_sizes, int n_in,
                              void* d_out, int out_size, void* d_ws, size_t ws_size,
                              hipStream_t stream) {
    const float* x  = (const float*)d_in[0];
    const int*   ei = (const int*)d_in[1];
    const float* W1 = (const float*)d_in[2];
    const float* b1 = (const float*)d_in[3];
    const float* W2 = (const float*)d_in[4];
    const float* b2 = (const float*)d_in[5];
    float* out = (float*)d_out;

    const int* row = ei;
    const int* col = ei + NE;

    // workspace layout
    int*   cnt  = (int*)d_ws;                 // NN
    int*   cur  = cnt + NN;                   // NN
    int*   off  = cur + NN;                   // NN+1 (padded to NN+4)
    int*   part = off + NN + 4;               // NBLK (padded to 100)
    float* dis  = (float*)(part + 100);       // NN
    int*   src  = (int*)(dis + NN);           // NE
    float* wgt  = (float*)(src + NE);         // NE
    float* h1   = wgt + NE;                   // NN*FH  (= split-K partial p0)
    float* hr   = h1 + (size_t)NN * FH;       // NN*FH  (= split-K partial p1, then relu output)
    float* h2   = h1;                         // reuse: h1 dead after k_gather1

    const int B = 256;
    int gbN = (NN + B - 1) / B;

    k_zero<<<(NN / 4 + B - 1) / B, B, 0, stream>>>((int4*)cnt, NN / 4);
    k_count<<<(NE / 4 + B - 1) / B, B, 0, stream>>>(col, cnt);
    k_dis<<<gbN, B, 0, stream>>>(cnt, dis);
    k_blocksum<<<NBLK, SCAN_B, 0, stream>>>(cnt, part);
    k_scanpart<<<1, 128, 0, stream>>>(part);
    k_scanblock<<<NBLK, SCAN_B, 0, stream>>>(cnt, part, off, cur);
    k_fill<<<(NE / 4 + B - 1) / B, B, 0, stream>>>(row, col, dis, cur, src, wgt);

    k_gemm1s<<<2 * GB1, B, 0, stream>>>(x, W1, h1, hr);
    k_comb<<<(NN * FH / 4 + B - 1) / B, B, 0, stream>>>(h1, hr);

    k_gather1<<<(NN * FH + B - 1) / B, B, 0, stream>>>(off, src, wgt, h1, dis, b1, hr);
    k_gemm2<<<gbN, B, 0, stream>>>(hr, W2, h2);
    k_gather2<<<(NN * FC + B - 1) / B, B, 0, stream>>>(off, src, wgt, h2, dis, b2, out);
}

// Round 6
// 341.864 us; speedup vs baseline: 1.2513x; 1.2513x over previous
//
#include <hip/hip_runtime.h>
#include <hip/hip_bf16.h>

#define NN 100000
#define NE 1600000
#define FIN 512
#define FH 32
#define FC 16
#define SCAN_B 1024
#define NBLK ((NN + SCAN_B - 1) / SCAN_B)  // 98
#define KHALF 256                          // split-K half size
#define GB1 ((NN + 255) / 256)             // 391 node-blocks
#define NCB ((NE / 4 + 255) / 256)         // 1563 count/fill blocks (ceiling!)
#define CSTR 16                            // cnt padding: one counter per 64B line

// ---------------- zero padded counters ----------------

__global__ void k_zero(int4* __restrict__ p, int n4) {
    int i = blockIdx.x * blockDim.x + threadIdx.x;
    if (i < n4) p[i] = make_int4(0, 0, 0, 0);
}

// ---------------- fused: degree count (with rank capture) + GEMM1 split-K ----------------
// blocks [0, NCB): count 4 edges/thread, rank = atomic return (u16)
// blocks [NCB, NCB+2*GB1): GEMM1 split-K halves

__global__ __launch_bounds__(256) void k_cnt_gemm1(const int* __restrict__ col,
                                                   int* __restrict__ cntp,
                                                   unsigned short* __restrict__ rank,
                                                   const float* __restrict__ x,
                                                   const float* __restrict__ W1,
                                                   float* __restrict__ p0,
                                                   float* __restrict__ p1) {
    __shared__ float Wl[KHALF * FH];  // 32 KB (used by gemm path only)

    if (blockIdx.x < NCB) {
        int i = blockIdx.x * 256 + threadIdx.x;  // edge-quad index
        if (i >= NE / 4) return;
        int4 c4 = ((const int4*)col)[i];
        ushort4 rk;
        rk.x = (unsigned short)atomicAdd(&cntp[c4.x * CSTR], 1);
        rk.y = (unsigned short)atomicAdd(&cntp[c4.y * CSTR], 1);
        rk.z = (unsigned short)atomicAdd(&cntp[c4.z * CSTR], 1);
        rk.w = (unsigned short)atomicAdd(&cntp[c4.w * CSTR], 1);
        ((ushort4*)rank)[i] = rk;
        return;
    }

    int b = blockIdx.x - NCB;
    int half = b & 1;
    int nb = b >> 1;
    int ks = half ? KHALF : 0;
    float* dst = half ? p1 : p0;

    const float4* wsrc = (const float4*)(W1 + (size_t)ks * FH);
    for (int i = threadIdx.x; i < KHALF * FH / 4; i += 256)
        ((float4*)Wl)[i] = wsrc[i];
    __syncthreads();

    int n = nb * 256 + threadIdx.x;
    if (n >= NN) return;

    float acc[FH];
#pragma unroll
    for (int j = 0; j < FH; ++j) acc[j] = 0.0f;

    const float4* xr = (const float4*)(x + (size_t)n * FIN + ks);
    for (int kg = 0; kg < KHALF / 4; kg += 8) {
        float4 xv[8];
#pragma unroll
        for (int u = 0; u < 8; ++u) xv[u] = xr[kg + u];
#pragma unroll
        for (int u = 0; u < 8; ++u) {
            const float* xs = (const float*)&xv[u];
#pragma unroll
            for (int kk = 0; kk < 4; ++kk) {
                float xk = xs[kk];
                const float* wrow = &Wl[((kg + u) * 4 + kk) * FH];
#pragma unroll
                for (int j = 0; j < FH; ++j) acc[j] += xk * wrow[j];
            }
        }
    }
    float4* outp = (float4*)(dst + (size_t)n * FH);
#pragma unroll
    for (int j = 0; j < FH / 4; ++j)
        outp[j] = make_float4(acc[4 * j], acc[4 * j + 1], acc[4 * j + 2], acc[4 * j + 3]);
}

// ---------------- fused: blocksum + dis + comb ----------------
// blocks [0,98): per-block degree sums; [98,196): dis = rsqrt(deg+1); rest: h1 += p1

__global__ __launch_bounds__(SCAN_B) void k_fused2(const int* __restrict__ cntp,
                                                   int* __restrict__ part,
                                                   float* __restrict__ dis,
                                                   float4* __restrict__ h1,
                                                   const float4* __restrict__ p1) {
    __shared__ int s[SCAN_B];
    int bid = blockIdx.x;
    if (bid < NBLK) {
        int i = bid * SCAN_B + threadIdx.x;
        s[threadIdx.x] = (i < NN) ? cntp[(size_t)i * CSTR] : 0;
        __syncthreads();
        for (int st = SCAN_B / 2; st > 0; st >>= 1) {
            if (threadIdx.x < st) s[threadIdx.x] += s[threadIdx.x + st];
            __syncthreads();
        }
        if (threadIdx.x == 0) part[bid] = s[0];
    } else if (bid < 2 * NBLK) {
        int n = (bid - NBLK) * SCAN_B + threadIdx.x;
        if (n < NN) dis[n] = rsqrtf((float)cntp[(size_t)n * CSTR] + 1.0f);
    } else {
        int idx = (bid - 2 * NBLK) * SCAN_B + threadIdx.x;
        if (idx < NN * FH / 4) {
            float4 a = h1[idx];
            float4 b = p1[idx];
            h1[idx] = make_float4(a.x + b.x, a.y + b.y, a.z + b.z, a.w + b.w);
        }
    }
}

// ---------------- scan of partials ----------------

__global__ __launch_bounds__(128) void k_scanpart(int* __restrict__ part) {
    __shared__ int s[128];
    int t = threadIdx.x;
    int v = (t < NBLK) ? part[t] : 0;
    s[t] = v;
    __syncthreads();
    for (int st = 1; st < 128; st <<= 1) {
        int a = (t >= st) ? s[t - st] : 0;
        __syncthreads();
        s[t] += a;
        __syncthreads();
    }
    if (t < NBLK) part[t] = s[t] - v;  // exclusive
}

__global__ __launch_bounds__(SCAN_B) void k_scanblock(const int* __restrict__ cntp,
                                                      const int* __restrict__ part,
                                                      int* __restrict__ off) {
    __shared__ int s[SCAN_B];
    int i = blockIdx.x * SCAN_B + threadIdx.x;
    int v = (i < NN) ? cntp[(size_t)i * CSTR] : 0;
    s[threadIdx.x] = v;
    __syncthreads();
    for (int st = 1; st < SCAN_B; st <<= 1) {
        int add = (threadIdx.x >= st) ? s[threadIdx.x - st] : 0;
        __syncthreads();
        s[threadIdx.x] += add;
        __syncthreads();
    }
    if (i < NN) off[i] = part[blockIdx.x] + s[threadIdx.x] - v;  // exclusive
    if (i == NN - 1) off[NN] = part[blockIdx.x] + s[threadIdx.x];
}

// ---------------- CSR fill: atomic-free, slot = off[col] + rank ----------------

__global__ void k_fill(const int* __restrict__ row, const int* __restrict__ col,
                       const unsigned short* __restrict__ rank,
                       const float* __restrict__ dis, const int* __restrict__ off,
                       int2* __restrict__ csr) {
    int i = blockIdx.x * blockDim.x + threadIdx.x;  // edge-quad index
    if (i >= NE / 4) return;
    int4 r4 = ((const int4*)row)[i];
    int4 c4 = ((const int4*)col)[i];
    ushort4 rk4 = ((const ushort4*)rank)[i];
    int rr[4] = {r4.x, r4.y, r4.z, r4.w};
    int cc[4] = {c4.x, c4.y, c4.z, c4.w};
    int rk[4] = {rk4.x, rk4.y, rk4.z, rk4.w};
    float dr[4], dc[4];
    int o4[4];
#pragma unroll
    for (int u = 0; u < 4; ++u) dr[u] = dis[rr[u]];
#pragma unroll
    for (int u = 0; u < 4; ++u) dc[u] = dis[cc[u]];
#pragma unroll
    for (int u = 0; u < 4; ++u) o4[u] = off[cc[u]];
#pragma unroll
    for (int u = 0; u < 4; ++u)
        csr[o4[u] + rk[u]] = make_int2(rr[u], __float_as_int(dr[u] * dc[u]));
}

// ---------------- gather layer1 + self-loop + bias + relu -> hr ----------------

__global__ __launch_bounds__(256) void k_gather1(const int* __restrict__ off,
                                                 const int2* __restrict__ csr,
                                                 const float* __restrict__ h1,
                                                 const float* __restrict__ dis,
                                                 const float* __restrict__ b1,
                                                 float* __restrict__ hr) {
    int g = blockIdx.x * (256 / FH) + threadIdx.x / FH;
    int f = threadIdx.x & (FH - 1);
    if (g >= NN) return;
    int s0 = off[g], s1 = off[g + 1];
    float acc = 0.0f;
    for (int i = s0; i < s1; ++i) {
        int2 ew = csr[i];
        acc += h1[(size_t)ew.x * FH + f] * __int_as_float(ew.y);
    }
    float d2 = dis[g] * dis[g];
    float v = acc + h1[(size_t)g * FH + f] * d2 + b1[f];
    hr[(size_t)g * FH + f] = v > 0.0f ? v : 0.0f;
}

// ---------------- GEMM2: h2 = hr @ W2 (32 -> 16) ----------------

__global__ __launch_bounds__(256) void k_gemm2(const float* __restrict__ hr,
                                               const float* __restrict__ W2,
                                               float* __restrict__ h2) {
    __shared__ float Wl[FH * FC];  // 2 KB
    for (int i = threadIdx.x; i < FH * FC; i += 256) Wl[i] = W2[i];
    __syncthreads();
    int n = blockIdx.x * blockDim.x + threadIdx.x;
    if (n >= NN) return;
    float h[FH];
    const float4* hp = (const float4*)(hr + (size_t)n * FH);
#pragma unroll
    for (int j = 0; j < FH / 4; ++j) {
        float4 t = hp[j];
        h[4 * j] = t.x; h[4 * j + 1] = t.y; h[4 * j + 2] = t.z; h[4 * j + 3] = t.w;
    }
#pragma unroll
    for (int j = 0; j < FC; ++j) {
        float s = 0.0f;
#pragma unroll
        for (int k = 0; k < FH; ++k) s += h[k] * Wl[k * FC + j];
        h2[(size_t)n * FC + j] = s;
    }
}

// ---------------- gather layer2 + self-loop + bias + log_softmax -> out ----------------

__global__ __launch_bounds__(256) void k_gather2(const int* __restrict__ off,
                                                 const int2* __restrict__ csr,
                                                 const float* __restrict__ h2,
                                                 const float* __restrict__ dis,
                                                 const float* __restrict__ b2,
                                                 float* __restrict__ out) {
    int g = blockIdx.x * (256 / FC) + threadIdx.x / FC;
    int f = threadIdx.x & (FC - 1);
    if (g >= NN) return;
    int s0 = off[g], s1 = off[g + 1];
    float acc = 0.0f;
    for (int i = s0; i < s1; ++i) {
        int2 ew = csr[i];
        acc += h2[(size_t)ew.x * FC + f] * __int_as_float(ew.y);
    }
    float d2 = dis[g] * dis[g];
    float v = acc + h2[(size_t)g * FC + f] * d2 + b2[f];
    float m = v;
#pragma unroll
    for (int o = 1; o < FC; o <<= 1) m = fmaxf(m, __shfl_xor(m, o, FC));
    float e = __expf(v - m);
    float s = e;
#pragma unroll
    for (int o = 1; o < FC; o <<= 1) s += __shfl_xor(s, o, FC);
    out[(size_t)g * FC + f] = v - m - logf(s);
}

extern "C" void kernel_launch(void* const* d_in, const int* in_sizes, int n_in,
                              void* d_out, int out_size, void* d_ws, size_t ws_size,
                              hipStream_t stream) {
    const float* x  = (const float*)d_in[0];
    const int*   ei = (const int*)d_in[1];
    const float* W1 = (const float*)d_in[2];
    const float* b1 = (const float*)d_in[3];
    const float* W2 = (const float*)d_in[4];
    const float* b2 = (const float*)d_in[5];
    float* out = (float*)d_out;

    const int* row = ei;
    const int* col = ei + NE;

    // workspace layout (int units; all regions 16B-aligned)
    int* base = (int*)d_ws;
    int*   cntp = base;                            // NN*CSTR = 1,600,000
    int*   off  = cntp + (size_t)NN * CSTR;        // NN+1 (pad to 100,008)
    int*   part = off + NN + 8;                    // 128
    unsigned short* rank = (unsigned short*)(part + 128);  // NE u16 = 800,000 ints
    float* dis  = (float*)(part + 128 + NE / 2);   // NN
    float* h1   = dis + NN;                        // NN*FH (split-K partial p0)
    float* p1   = h1 + (size_t)NN * FH;            // NN*FH (split-K partial; csr aliases after comb)
    float* hr   = p1 + (size_t)NN * FH;            // NN*FH
    int2*  csr  = (int2*)p1;                       // NE int2, aliases dead p1
    float* h2   = h1;                              // reuse: h1 dead after k_gather1

    const int B = 256;

    k_zero<<<(NN * CSTR / 4 + B - 1) / B, B, 0, stream>>>((int4*)cntp, NN * CSTR / 4);
    k_cnt_gemm1<<<NCB + 2 * GB1, B, 0, stream>>>(col, cntp, rank, x, W1, h1, p1);
    k_fused2<<<2 * NBLK + (NN * FH / 4 + SCAN_B - 1) / SCAN_B, SCAN_B, 0, stream>>>(
        cntp, part, dis, (float4*)h1, (const float4*)p1);
    k_scanpart<<<1, 128, 0, stream>>>(part);
    k_scanblock<<<NBLK, SCAN_B, 0, stream>>>(cntp, part, off);
    k_fill<<<NCB, B, 0, stream>>>(row, col, rank, dis, off, csr);

    k_gather1<<<(NN * FH + B - 1) / B, B, 0, stream>>>(off, csr, h1, dis, b1, hr);
    k_gemm2<<<(NN + B - 1) / B, B, 0, stream>>>(hr, W2, h2);
    k_gather2<<<(NN * FC + B - 1) / B, B, 0, stream>>>(off, csr, h2, dis, b2, out);
}

// Round 7
// 320.919 us; speedup vs baseline: 1.3330x; 1.0653x over previous
//
#include <hip/hip_runtime.h>
#include <hip/hip_bf16.h>

#define NN 100000
#define NE 1600000
#define FIN 512
#define FH 32
#define FC 16
#define SCAN_B 1024
#define NBLK ((NN + SCAN_B - 1) / SCAN_B)  // 98
#define KHALF 256                          // split-K half size
#define GB1 ((NN + 255) / 256)             // 391 node-blocks
#define NCB ((NE / 4 + 255) / 256)         // 1563 fill blocks (ceiling!)
#define M_SL 16                            // edge slices
#define SLICE (NE / M_SL)                  // 100000 edges/slice
#define QSL (SLICE / 4)                    // 25000 quads/slice
#define PSZ 12800                          // nodes per partition (LDS bins)
#define NP ((NN + PSZ - 1) / PSZ)          // 8 partitions
#define NHB (NP * M_SL)                    // 128 hist blocks

// ---------------- fused: LDS-binned count+rank  +  GEMM1 split-K ----------------
// blocks [0, NHB): partition p = b/M_SL, slice m = b%M_SL.
//   LDS histogram over cols in [p*PSZ, p*PSZ+PSZ); LDS atomic return = local rank.
//   Writes rank[e] (u16) and ghist[m][c] (per-slice count).
// blocks [NHB, NHB+2*GB1): GEMM1 split-K halves (Wl reuses the hist LDS buffer).

__global__ __launch_bounds__(256) void k_hist_gemm1(const int* __restrict__ col,
                                                    int* __restrict__ ghist,
                                                    unsigned short* __restrict__ rank,
                                                    const float* __restrict__ x,
                                                    const float* __restrict__ W1,
                                                    float* __restrict__ p0,
                                                    float* __restrict__ p1) {
    __shared__ int sh[PSZ];  // 51.2 KB; gemm path reuses as float W-tile (needs 32 KB)

    if (blockIdx.x < NHB) {
        int p = blockIdx.x / M_SL;
        int m = blockIdx.x % M_SL;
        int base = p * PSZ;
        int nb = min(PSZ, NN - base);
        for (int i = threadIdx.x; i < nb; i += 256) sh[i] = 0;
        __syncthreads();
        const int4* c4p = (const int4*)(col + m * SLICE);
        for (int it = 0; it < (QSL + 255) / 256; ++it) {
            int q = it * 256 + threadIdx.x;
            if (q < QSL) {
                int4 c4 = c4p[q];
                int e = (m * QSL + q) * 4;
                int cc[4] = {c4.x, c4.y, c4.z, c4.w};
#pragma unroll
                for (int u = 0; u < 4; ++u) {
                    int d = cc[u] - base;
                    if ((unsigned)d < (unsigned)nb) {
                        int lr = atomicAdd(&sh[d], 1);
                        rank[e + u] = (unsigned short)lr;
                    }
                }
            }
        }
        __syncthreads();
        for (int i = threadIdx.x; i < nb; i += 256)
            ghist[(size_t)m * NN + base + i] = sh[i];
        return;
    }

    // ---- GEMM1 split-K ----
    float* Wl = (float*)sh;
    int b = blockIdx.x - NHB;
    int half = b & 1;
    int nb2 = b >> 1;
    int ks = half ? KHALF : 0;
    float* dst = half ? p1 : p0;

    const float4* wsrc = (const float4*)(W1 + (size_t)ks * FH);
    for (int i = threadIdx.x; i < KHALF * FH / 4; i += 256)
        ((float4*)Wl)[i] = wsrc[i];
    __syncthreads();

    int n = nb2 * 256 + threadIdx.x;
    if (n >= NN) return;

    float acc[FH];
#pragma unroll
    for (int j = 0; j < FH; ++j) acc[j] = 0.0f;

    const float4* xr = (const float4*)(x + (size_t)n * FIN + ks);
    for (int kg = 0; kg < KHALF / 4; kg += 8) {
        float4 xv[8];
#pragma unroll
        for (int u = 0; u < 8; ++u) xv[u] = xr[kg + u];
#pragma unroll
        for (int u = 0; u < 8; ++u) {
            const float* xs = (const float*)&xv[u];
#pragma unroll
            for (int kk = 0; kk < 4; ++kk) {
                float xk = xs[kk];
                const float* wrow = &Wl[((kg + u) * 4 + kk) * FH];
#pragma unroll
                for (int j = 0; j < FH; ++j) acc[j] += xk * wrow[j];
            }
        }
    }
    float4* outp = (float4*)(dst + (size_t)n * FH);
#pragma unroll
    for (int j = 0; j < FH / 4; ++j)
        outp[j] = make_float4(acc[4 * j], acc[4 * j + 1], acc[4 * j + 2], acc[4 * j + 3]);
}

// ---------------- fused: per-node slice-scan (+cnt+dis+part)  +  split-K combine ----------------
// blocks [0, NBLK): exclusive prefix of ghist[*][c] over slices; cnt, dis, block-sum -> part
// blocks [NBLK, ...): h1 += p1

__global__ __launch_bounds__(SCAN_B) void k_xscan(int* __restrict__ ghist,
                                                  int* __restrict__ cnt,
                                                  float* __restrict__ dis,
                                                  int* __restrict__ part,
                                                  float4* __restrict__ h1,
                                                  const float4* __restrict__ p1) {
    __shared__ int s[SCAN_B];
    int bid = blockIdx.x;
    if (bid < NBLK) {
        int c = bid * SCAN_B + threadIdx.x;
        int sum = 0;
        if (c < NN) {
#pragma unroll 4
            for (int m = 0; m < M_SL; ++m) {
                size_t idx = (size_t)m * NN + c;
                int t = ghist[idx];
                ghist[idx] = sum;  // exclusive prefix (block offset)
                sum += t;
            }
            cnt[c] = sum;
            dis[c] = rsqrtf((float)sum + 1.0f);  // +1 self-loop
        }
        s[threadIdx.x] = sum;
        __syncthreads();
        for (int st = SCAN_B / 2; st > 0; st >>= 1) {
            if (threadIdx.x < st) s[threadIdx.x] += s[threadIdx.x + st];
            __syncthreads();
        }
        if (threadIdx.x == 0) part[bid] = s[0];
    } else {
        int idx = (bid - NBLK) * SCAN_B + threadIdx.x;
        if (idx < NN * FH / 4) {
            float4 a = h1[idx];
            float4 b = p1[idx];
            h1[idx] = make_float4(a.x + b.x, a.y + b.y, a.z + b.z, a.w + b.w);
        }
    }
}

// ---------------- scan of partials ----------------

__global__ __launch_bounds__(128) void k_scanpart(int* __restrict__ part) {
    __shared__ int s[128];
    int t = threadIdx.x;
    int v = (t < NBLK) ? part[t] : 0;
    s[t] = v;
    __syncthreads();
    for (int st = 1; st < 128; st <<= 1) {
        int a = (t >= st) ? s[t - st] : 0;
        __syncthreads();
        s[t] += a;
        __syncthreads();
    }
    if (t < NBLK) part[t] = s[t] - v;  // exclusive
}

__global__ __launch_bounds__(SCAN_B) void k_scanblock(const int* __restrict__ cnt,
                                                      const int* __restrict__ part,
                                                      int* __restrict__ off) {
    __shared__ int s[SCAN_B];
    int i = blockIdx.x * SCAN_B + threadIdx.x;
    int v = (i < NN) ? cnt[i] : 0;
    s[threadIdx.x] = v;
    __syncthreads();
    for (int st = 1; st < SCAN_B; st <<= 1) {
        int add = (threadIdx.x >= st) ? s[threadIdx.x - st] : 0;
        __syncthreads();
        s[threadIdx.x] += add;
        __syncthreads();
    }
    if (i < NN) off[i] = part[blockIdx.x] + s[threadIdx.x] - v;  // exclusive
    if (i == NN - 1) off[NN] = part[blockIdx.x] + s[threadIdx.x];
}

// ---------------- CSR fill: atomic-free, slot = off[c] + ghist[m][c] + rank ----------------

__global__ void k_fill(const int* __restrict__ row, const int* __restrict__ col,
                       const unsigned short* __restrict__ rank,
                       const float* __restrict__ dis, const int* __restrict__ off,
                       const int* __restrict__ ghist, int2* __restrict__ csr) {
    int i = blockIdx.x * blockDim.x + threadIdx.x;  // global quad index
    if (i >= NE / 4) return;
    int m = i / QSL;  // slice
    int4 r4 = ((const int4*)row)[i];
    int4 c4 = ((const int4*)col)[i];
    ushort4 rk4 = ((const ushort4*)rank)[i];
    int rr[4] = {r4.x, r4.y, r4.z, r4.w};
    int cc[4] = {c4.x, c4.y, c4.z, c4.w};
    int rk[4] = {rk4.x, rk4.y, rk4.z, rk4.w};
    float dr[4], dc[4];
    int o4[4], bp[4];
#pragma unroll
    for (int u = 0; u < 4; ++u) dr[u] = dis[rr[u]];
#pragma unroll
    for (int u = 0; u < 4; ++u) dc[u] = dis[cc[u]];
#pragma unroll
    for (int u = 0; u < 4; ++u) o4[u] = off[cc[u]];
#pragma unroll
    for (int u = 0; u < 4; ++u) bp[u] = ghist[(size_t)m * NN + cc[u]];
#pragma unroll
    for (int u = 0; u < 4; ++u)
        csr[o4[u] + bp[u] + rk[u]] = make_int2(rr[u], __float_as_int(dr[u] * dc[u]));
}

// ---------------- gather layer1 + self-loop + bias + relu -> hr ----------------

__global__ __launch_bounds__(256) void k_gather1(const int* __restrict__ off,
                                                 const int2* __restrict__ csr,
                                                 const float* __restrict__ h1,
                                                 const float* __restrict__ dis,
                                                 const float* __restrict__ b1,
                                                 float* __restrict__ hr) {
    int g = blockIdx.x * (256 / FH) + threadIdx.x / FH;
    int f = threadIdx.x & (FH - 1);
    if (g >= NN) return;
    int s0 = off[g], s1 = off[g + 1];
    float acc = 0.0f;
    for (int i = s0; i < s1; ++i) {
        int2 ew = csr[i];
        acc += h1[(size_t)ew.x * FH + f] * __int_as_float(ew.y);
    }
    float d2 = dis[g] * dis[g];
    float v = acc + h1[(size_t)g * FH + f] * d2 + b1[f];
    hr[(size_t)g * FH + f] = v > 0.0f ? v : 0.0f;
}

// ---------------- GEMM2: h2 = hr @ W2 (32 -> 16) ----------------

__global__ __launch_bounds__(256) void k_gemm2(const float* __restrict__ hr,
                                               const float* __restrict__ W2,
                                               float* __restrict__ h2) {
    __shared__ float Wl[FH * FC];  // 2 KB
    for (int i = threadIdx.x; i < FH * FC; i += 256) Wl[i] = W2[i];
    __syncthreads();
    int n = blockIdx.x * blockDim.x + threadIdx.x;
    if (n >= NN) return;
    float h[FH];
    const float4* hp = (const float4*)(hr + (size_t)n * FH);
#pragma unroll
    for (int j = 0; j < FH / 4; ++j) {
        float4 t = hp[j];
        h[4 * j] = t.x; h[4 * j + 1] = t.y; h[4 * j + 2] = t.z; h[4 * j + 3] = t.w;
    }
#pragma unroll
    for (int j = 0; j < FC; ++j) {
        float s = 0.0f;
#pragma unroll
        for (int k = 0; k < FH; ++k) s += h[k] * Wl[k * FC + j];
        h2[(size_t)n * FC + j] = s;
    }
}

// ---------------- gather layer2 + self-loop + bias + log_softmax -> out ----------------

__global__ __launch_bounds__(256) void k_gather2(const int* __restrict__ off,
                                                 const int2* __restrict__ csr,
                                                 const float* __restrict__ h2,
                                                 const float* __restrict__ dis,
                                                 const float* __restrict__ b2,
                                                 float* __restrict__ out) {
    int g = blockIdx.x * (256 / FC) + threadIdx.x / FC;
    int f = threadIdx.x & (FC - 1);
    if (g >= NN) return;
    int s0 = off[g], s1 = off[g + 1];
    float acc = 0.0f;
    for (int i = s0; i < s1; ++i) {
        int2 ew = csr[i];
        acc += h2[(size_t)ew.x * FC + f] * __int_as_float(ew.y);
    }
    float d2 = dis[g] * dis[g];
    float v = acc + h2[(size_t)g * FC + f] * d2 + b2[f];
    float m = v;
#pragma unroll
    for (int o = 1; o < FC; o <<= 1) m = fmaxf(m, __shfl_xor(m, o, FC));
    float e = __expf(v - m);
    float s = e;
#pragma unroll
    for (int o = 1; o < FC; o <<= 1) s += __shfl_xor(s, o, FC);
    out[(size_t)g * FC + f] = v - m - logf(s);
}

extern "C" void kernel_launch(void* const* d_in, const int* in_sizes, int n_in,
                              void* d_out, int out_size, void* d_ws, size_t ws_size,
                              hipStream_t stream) {
    const float* x  = (const float*)d_in[0];
    const int*   ei = (const int*)d_in[1];
    const float* W1 = (const float*)d_in[2];
    const float* b1 = (const float*)d_in[3];
    const float* W2 = (const float*)d_in[4];
    const float* b2 = (const float*)d_in[5];
    float* out = (float*)d_out;

    const int* row = ei;
    const int* col = ei + NE;

    // workspace layout (int units; ~49.2 MB total)
    int* base = (int*)d_ws;
    int*   ghist = base;                            // M_SL*NN = 1,600,000
    int*   cnt   = ghist + (size_t)M_SL * NN;       // NN
    int*   off   = cnt + NN;                        // NN+1 (pad to NN+8)
    int*   part  = off + NN + 8;                    // 128
    unsigned short* rank = (unsigned short*)(part + 128);  // NE u16 = 800,000 ints
    float* dis   = (float*)(part + 128 + NE / 2);   // NN
    float* h1    = dis + NN;                        // NN*FH (split-K partial p0)
    float* p1    = h1 + (size_t)NN * FH;            // NN*FH (partial; csr aliases after comb)
    float* hr    = p1 + (size_t)NN * FH;            // NN*FH
    int2*  csr   = (int2*)p1;                       // NE int2, aliases dead p1
    float* h2    = h1;                              // reuse: h1 dead after k_gather1

    const int B = 256;

    k_hist_gemm1<<<NHB + 2 * GB1, B, 0, stream>>>(col, ghist, rank, x, W1, h1, p1);
    k_xscan<<<NBLK + (NN * FH / 4 + SCAN_B - 1) / SCAN_B, SCAN_B, 0, stream>>>(
        ghist, cnt, dis, part, (float4*)h1, (const float4*)p1);
    k_scanpart<<<1, 128, 0, stream>>>(part);
    k_scanblock<<<NBLK, SCAN_B, 0, stream>>>(cnt, part, off);
    k_fill<<<NCB, B, 0, stream>>>(row, col, rank, dis, off, ghist, csr);

    k_gather1<<<(NN * FH + B - 1) / B, B, 0, stream>>>(off, csr, h1, dis, b1, hr);
    k_gemm2<<<(NN + B - 1) / B, B, 0, stream>>>(hr, W2, h2);
    k_gather2<<<(NN * FC + B - 1) / B, B, 0, stream>>>(off, csr, h2, dis, b2, out);
}

// Round 8
// 320.434 us; speedup vs baseline: 1.3350x; 1.0015x over previous
//
#include <hip/hip_runtime.h>
#include <hip/hip_bf16.h>

#define NN 100000
#define NE 1600000
#define FIN 512
#define FH 32
#define FC 16
#define SCAN_B 1024
#define NBLK ((NN + SCAN_B - 1) / SCAN_B)  // 98
#define KHALF 256                          // split-K half size
#define NCB ((NE / 4 + 255) / 256)         // 1563 fill blocks (ceiling!)
#define M_SL 16                            // edge slices
#define SLICE (NE / M_SL)                  // 100000 edges/slice
#define QSL (SLICE / 4)                    // 25000 quads/slice
#define PSZ 8192                           // nodes per partition (32 KB LDS bins)
#define NP ((NN + PSZ - 1) / PSZ)          // 13 partitions
#define NHB (NP * M_SL)                    // 208 hist blocks
#define NPB 512                            // nodes per GEMM block (256 thr x 2)
#define NB2 ((NN + NPB - 1) / NPB)         // 196 GEMM node-blocks
#define NGB (2 * NB2)                      // 392 GEMM blocks (2 K-halves)

// ---------------- fused: GEMM1 split-K (2 nodes/thread)  +  LDS-binned count+rank ----------------
// blocks [0, NGB): GEMM1; blocks [NGB, NGB+NHB): histogram partition p, slice m.

__global__ __launch_bounds__(256) void k_hist_gemm1(const int* __restrict__ col,
                                                    int* __restrict__ ghist,
                                                    unsigned short* __restrict__ rank,
                                                    const float* __restrict__ x,
                                                    const float* __restrict__ W1,
                                                    float* __restrict__ p0,
                                                    float* __restrict__ p1) {
    __shared__ int sh[PSZ];  // 32 KB; gemm path reuses as float W-tile (32 KB)

    if (blockIdx.x >= NGB) {
        int hb = blockIdx.x - NGB;
        int p = hb / M_SL;
        int m = hb % M_SL;
        int base = p * PSZ;
        int nb = min(PSZ, NN - base);
        for (int i = threadIdx.x; i < nb; i += 256) sh[i] = 0;
        __syncthreads();
        const int4* c4p = (const int4*)(col + m * SLICE);
        for (int it = 0; it < (QSL + 255) / 256; ++it) {
            int q = it * 256 + threadIdx.x;
            if (q < QSL) {
                int4 c4 = c4p[q];
                int e = (m * QSL + q) * 4;
                int cc[4] = {c4.x, c4.y, c4.z, c4.w};
#pragma unroll
                for (int u = 0; u < 4; ++u) {
                    int d = cc[u] - base;
                    if ((unsigned)d < (unsigned)nb) {
                        int lr = atomicAdd(&sh[d], 1);
                        rank[e + u] = (unsigned short)lr;
                    }
                }
            }
        }
        __syncthreads();
        for (int i = threadIdx.x; i < nb; i += 256)
            ghist[(size_t)m * NN + base + i] = sh[i];
        return;
    }

    // ---- GEMM1 split-K, 2 nodes per thread ----
    float* Wl = (float*)sh;
    int b = blockIdx.x;
    int half = b & 1;
    int nb2 = b >> 1;
    int ks = half ? KHALF : 0;
    float* dst = half ? p1 : p0;

    const float4* wsrc = (const float4*)(W1 + (size_t)ks * FH);
    for (int i = threadIdx.x; i < KHALF * FH / 4; i += 256)
        ((float4*)Wl)[i] = wsrc[i];
    __syncthreads();

    int n0 = nb2 * NPB + threadIdx.x;
    int n1 = n0 + 256;
    bool v0 = n0 < NN, v1 = n1 < NN;

    float acc0[FH], acc1[FH];
#pragma unroll
    for (int j = 0; j < FH; ++j) { acc0[j] = 0.0f; acc1[j] = 0.0f; }

    const float4* xr0 = (const float4*)(x + (size_t)n0 * FIN + ks);
    const float4* xr1 = (const float4*)(x + (size_t)n1 * FIN + ks);
    for (int kg = 0; kg < KHALF / 4; kg += 4) {
        float4 a0[4], a1[4];
        if (v0) {
#pragma unroll
            for (int u = 0; u < 4; ++u) a0[u] = xr0[kg + u];
        }
        if (v1) {
#pragma unroll
            for (int u = 0; u < 4; ++u) a1[u] = xr1[kg + u];
        }
#pragma unroll
        for (int u = 0; u < 4; ++u) {
            const float* s0 = (const float*)&a0[u];
            const float* s1 = (const float*)&a1[u];
#pragma unroll
            for (int kk = 0; kk < 4; ++kk) {
                float x0 = s0[kk], x1 = s1[kk];
                const float* wrow = &Wl[((kg + u) * 4 + kk) * FH];
#pragma unroll
                for (int j = 0; j < FH; ++j) {
                    acc0[j] += x0 * wrow[j];
                    acc1[j] += x1 * wrow[j];
                }
            }
        }
    }
    if (v0) {
        float4* outp = (float4*)(dst + (size_t)n0 * FH);
#pragma unroll
        for (int j = 0; j < FH / 4; ++j)
            outp[j] = make_float4(acc0[4 * j], acc0[4 * j + 1], acc0[4 * j + 2], acc0[4 * j + 3]);
    }
    if (v1) {
        float4* outp = (float4*)(dst + (size_t)n1 * FH);
#pragma unroll
        for (int j = 0; j < FH / 4; ++j)
            outp[j] = make_float4(acc1[4 * j], acc1[4 * j + 1], acc1[4 * j + 2], acc1[4 * j + 3]);
    }
}

// ---------------- fused: per-node slice-scan (+cnt+dis+part)  +  split-K combine ----------------

__global__ __launch_bounds__(SCAN_B) void k_xscan(int* __restrict__ ghist,
                                                  int* __restrict__ cnt,
                                                  float* __restrict__ dis,
                                                  int* __restrict__ part,
                                                  float4* __restrict__ h1,
                                                  const float4* __restrict__ p1) {
    __shared__ int s[SCAN_B];
    int bid = blockIdx.x;
    if (bid < NBLK) {
        int c = bid * SCAN_B + threadIdx.x;
        int sum = 0;
        if (c < NN) {
#pragma unroll 4
            for (int m = 0; m < M_SL; ++m) {
                size_t idx = (size_t)m * NN + c;
                int t = ghist[idx];
                ghist[idx] = sum;  // exclusive prefix (block offset)
                sum += t;
            }
            cnt[c] = sum;
            dis[c] = rsqrtf((float)sum + 1.0f);  // +1 self-loop
        }
        s[threadIdx.x] = sum;
        __syncthreads();
        for (int st = SCAN_B / 2; st > 0; st >>= 1) {
            if (threadIdx.x < st) s[threadIdx.x] += s[threadIdx.x + st];
            __syncthreads();
        }
        if (threadIdx.x == 0) part[bid] = s[0];
    } else {
        int idx = (bid - NBLK) * SCAN_B + threadIdx.x;
        if (idx < NN * FH / 4) {
            float4 a = h1[idx];
            float4 b = p1[idx];
            h1[idx] = make_float4(a.x + b.x, a.y + b.y, a.z + b.z, a.w + b.w);
        }
    }
}

// ---------------- scan of partials ----------------

__global__ __launch_bounds__(128) void k_scanpart(int* __restrict__ part) {
    __shared__ int s[128];
    int t = threadIdx.x;
    int v = (t < NBLK) ? part[t] : 0;
    s[t] = v;
    __syncthreads();
    for (int st = 1; st < 128; st <<= 1) {
        int a = (t >= st) ? s[t - st] : 0;
        __syncthreads();
        s[t] += a;
        __syncthreads();
    }
    if (t < NBLK) part[t] = s[t] - v;  // exclusive
}

__global__ __launch_bounds__(SCAN_B) void k_scanblock(const int* __restrict__ cnt,
                                                      const int* __restrict__ part,
                                                      int* __restrict__ off) {
    __shared__ int s[SCAN_B];
    int i = blockIdx.x * SCAN_B + threadIdx.x;
    int v = (i < NN) ? cnt[i] : 0;
    s[threadIdx.x] = v;
    __syncthreads();
    for (int st = 1; st < SCAN_B; st <<= 1) {
        int add = (threadIdx.x >= st) ? s[threadIdx.x - st] : 0;
        __syncthreads();
        s[threadIdx.x] += add;
        __syncthreads();
    }
    if (i < NN) off[i] = part[blockIdx.x] + s[threadIdx.x] - v;  // exclusive
    if (i == NN - 1) off[NN] = part[blockIdx.x] + s[threadIdx.x];
}

// ---------------- CSR fill: atomic-free, slot = off[c] + ghist[m][c] + rank ----------------

__global__ void k_fill(const int* __restrict__ row, const int* __restrict__ col,
                       const unsigned short* __restrict__ rank,
                       const float* __restrict__ dis, const int* __restrict__ off,
                       const int* __restrict__ ghist, int2* __restrict__ csr) {
    int i = blockIdx.x * blockDim.x + threadIdx.x;  // global quad index
    if (i >= NE / 4) return;
    int m = i / QSL;  // slice
    int4 r4 = ((const int4*)row)[i];
    int4 c4 = ((const int4*)col)[i];
    ushort4 rk4 = ((const ushort4*)rank)[i];
    int rr[4] = {r4.x, r4.y, r4.z, r4.w};
    int cc[4] = {c4.x, c4.y, c4.z, c4.w};
    int rk[4] = {rk4.x, rk4.y, rk4.z, rk4.w};
    float dr[4], dc[4];
    int o4[4], bp[4];
#pragma unroll
    for (int u = 0; u < 4; ++u) dr[u] = dis[rr[u]];
#pragma unroll
    for (int u = 0; u < 4; ++u) dc[u] = dis[cc[u]];
#pragma unroll
    for (int u = 0; u < 4; ++u) o4[u] = off[cc[u]];
#pragma unroll
    for (int u = 0; u < 4; ++u) bp[u] = ghist[(size_t)m * NN + cc[u]];
#pragma unroll
    for (int u = 0; u < 4; ++u)
        csr[o4[u] + bp[u] + rk[u]] = make_int2(rr[u], __float_as_int(dr[u] * dc[u]));
}

// ---------------- gather layer1 + self-loop + bias + relu -> hr ----------------

__global__ __launch_bounds__(256) void k_gather1(const int* __restrict__ off,
                                                 const int2* __restrict__ csr,
                                                 const float* __restrict__ h1,
                                                 const float* __restrict__ dis,
                                                 const float* __restrict__ b1,
                                                 float* __restrict__ hr) {
    int g = blockIdx.x * (256 / FH) + threadIdx.x / FH;
    int f = threadIdx.x & (FH - 1);
    if (g >= NN) return;
    int s0 = off[g], s1 = off[g + 1];
    float acc = 0.0f;
    for (int i = s0; i < s1; ++i) {
        int2 ew = csr[i];
        acc += h1[(size_t)ew.x * FH + f] * __int_as_float(ew.y);
    }
    float d2 = dis[g] * dis[g];
    float v = acc + h1[(size_t)g * FH + f] * d2 + b1[f];
    hr[(size_t)g * FH + f] = v > 0.0f ? v : 0.0f;
}

// ---------------- GEMM2: h2 = hr @ W2 (32 -> 16) ----------------

__global__ __launch_bounds__(256) void k_gemm2(const float* __restrict__ hr,
                                               const float* __restrict__ W2,
                                               float* __restrict__ h2) {
    __shared__ float Wl[FH * FC];  // 2 KB
    for (int i = threadIdx.x; i < FH * FC; i += 256) Wl[i] = W2[i];
    __syncthreads();
    int n = blockIdx.x * blockDim.x + threadIdx.x;
    if (n >= NN) return;
    float h[FH];
    const float4* hp = (const float4*)(hr + (size_t)n * FH);
#pragma unroll
    for (int j = 0; j < FH / 4; ++j) {
        float4 t = hp[j];
        h[4 * j] = t.x; h[4 * j + 1] = t.y; h[4 * j + 2] = t.z; h[4 * j + 3] = t.w;
    }
#pragma unroll
    for (int j = 0; j < FC; ++j) {
        float s = 0.0f;
#pragma unroll
        for (int k = 0; k < FH; ++k) s += h[k] * Wl[k * FC + j];
        h2[(size_t)n * FC + j] = s;
    }
}

// ---------------- gather layer2 + self-loop + bias + log_softmax -> out ----------------

__global__ __launch_bounds__(256) void k_gather2(const int* __restrict__ off,
                                                 const int2* __restrict__ csr,
                                                 const float* __restrict__ h2,
                                                 const float* __restrict__ dis,
                                                 const float* __restrict__ b2,
                                                 float* __restrict__ out) {
    int g = blockIdx.x * (256 / FC) + threadIdx.x / FC;
    int f = threadIdx.x & (FC - 1);
    if (g >= NN) return;
    int s0 = off[g], s1 = off[g + 1];
    float acc = 0.0f;
    for (int i = s0; i < s1; ++i) {
        int2 ew = csr[i];
        acc += h2[(size_t)ew.x * FC + f] * __int_as_float(ew.y);
    }
    float d2 = dis[g] * dis[g];
    float v = acc + h2[(size_t)g * FC + f] * d2 + b2[f];
    float m = v;
#pragma unroll
    for (int o = 1; o < FC; o <<= 1) m = fmaxf(m, __shfl_xor(m, o, FC));
    float e = __expf(v - m);
    float s = e;
#pragma unroll
    for (int o = 1; o < FC; o <<= 1) s += __shfl_xor(s, o, FC);
    out[(size_t)g * FC + f] = v - m - logf(s);
}

extern "C" void kernel_launch(void* const* d_in, const int* in_sizes, int n_in,
                              void* d_out, int out_size, void* d_ws, size_t ws_size,
                              hipStream_t stream) {
    const float* x  = (const float*)d_in[0];
    const int*   ei = (const int*)d_in[1];
    const float* W1 = (const float*)d_in[2];
    const float* b1 = (const float*)d_in[3];
    const float* W2 = (const float*)d_in[4];
    const float* b2 = (const float*)d_in[5];
    float* out = (float*)d_out;

    const int* row = ei;
    const int* col = ei + NE;

    // workspace layout (int units; ~49.2 MB total)
    int* base = (int*)d_ws;
    int*   ghist = base;                            // M_SL*NN = 1,600,000
    int*   cnt   = ghist + (size_t)M_SL * NN;       // NN
    int*   off   = cnt + NN;                        // NN+1 (pad to NN+8)
    int*   part  = off + NN + 8;                    // 128
    unsigned short* rank = (unsigned short*)(part + 128);  // NE u16 = 800,000 ints
    float* dis   = (float*)(part + 128 + NE / 2);   // NN
    float* h1    = dis + NN;                        // NN*FH (split-K partial p0)
    float* p1    = h1 + (size_t)NN * FH;            // NN*FH (partial; csr aliases after comb)
    float* hr    = p1 + (size_t)NN * FH;            // NN*FH
    int2*  csr   = (int2*)p1;                       // NE int2, aliases dead p1
    float* h2    = h1;                              // reuse: h1 dead after k_gather1

    const int B = 256;

    k_hist_gemm1<<<NGB + NHB, B, 0, stream>>>(col, ghist, rank, x, W1, h1, p1);
    k_xscan<<<NBLK + (NN * FH / 4 + SCAN_B - 1) / SCAN_B, SCAN_B, 0, stream>>>(
        ghist, cnt, dis, part, (float4*)h1, (const float4*)p1);
    k_scanpart<<<1, 128, 0, stream>>>(part);
    k_scanblock<<<NBLK, SCAN_B, 0, stream>>>(cnt, part, off);
    k_fill<<<NCB, B, 0, stream>>>(row, col, rank, dis, off, ghist, csr);

    k_gather1<<<(NN * FH + B - 1) / B, B, 0, stream>>>(off, csr, h1, dis, b1, hr);
    k_gemm2<<<(NN + B - 1) / B, B, 0, stream>>>(hr, W2, h2);
    k_gather2<<<(NN * FC + B - 1) / B, B, 0, stream>>>(off, csr, h2, dis, b2, out);
}

// Round 9
// 280.292 us; speedup vs baseline: 1.5262x; 1.1432x over previous
//
#include <hip/hip_runtime.h>
#include <hip/hip_bf16.h>

#define NN 100000
#define NE 1600000
#define FIN 512
#define FH 32
#define FC 16
#define SCAN_B 1024
#define NBLK ((NN + SCAN_B - 1) / SCAN_B)  // 98
#define NCB ((NE / 4 + 255) / 256)         // 1563 fill blocks
#define M_SL 16                            // edge slices
#define SLICE (NE / M_SL)                  // 100000 edges/slice
#define QSL (SLICE / 4)                    // 25000 quads/slice
#define PSZ 8192                           // nodes per partition (32 KB LDS bins)
#define NP ((NN + PSZ - 1) / PSZ)          // 13 partitions
#define NHB (NP * M_SL)                    // 208 hist blocks
#define NGB1 ((NN + 63) / 64)              // 1563 MFMA gemm blocks (64 nodes each)

typedef __attribute__((ext_vector_type(8))) short bf16x8;
typedef __attribute__((ext_vector_type(4))) float f32x4;

__device__ inline unsigned short f2bf(float f) {
    unsigned u = __float_as_uint(f);
    return (unsigned short)((u + 0x7FFFu + ((u >> 16) & 1u)) >> 16);  // RNE
}

// ---------------- fused: LDS-binned count+rank  +  MFMA GEMM1 ----------------
// blocks [0, NHB): histogram partition p = b/M_SL, slice m = b%M_SL.
// blocks [NHB, NHB+NGB1): bf16 MFMA GEMM h1 = x @ W1 (64 nodes/block).

__global__ __launch_bounds__(256) void k_hist_gemm1(const int* __restrict__ col,
                                                    int* __restrict__ ghist,
                                                    unsigned short* __restrict__ rank,
                                                    const float* __restrict__ x,
                                                    const float* __restrict__ W1,
                                                    float* __restrict__ h1) {
    __shared__ int sh[PSZ];  // 32 KB; gemm path reuses as bf16 W-fragment store

    if (blockIdx.x < NHB) {
        int p = blockIdx.x / M_SL;
        int m = blockIdx.x % M_SL;
        int base = p * PSZ;
        int nb = min(PSZ, NN - base);
        for (int i = threadIdx.x; i < nb; i += 256) sh[i] = 0;
        __syncthreads();
        const int4* c4p = (const int4*)(col + m * SLICE);
        for (int it = 0; it < (QSL + 255) / 256; ++it) {
            int q = it * 256 + threadIdx.x;
            if (q < QSL) {
                int4 c4 = c4p[q];
                int e = (m * QSL + q) * 4;
                int cc[4] = {c4.x, c4.y, c4.z, c4.w};
#pragma unroll
                for (int u = 0; u < 4; ++u) {
                    int d = cc[u] - base;
                    if ((unsigned)d < (unsigned)nb) {
                        int lr = atomicAdd(&sh[d], 1);
                        rank[e + u] = (unsigned short)lr;
                    }
                }
            }
        }
        __syncthreads();
        for (int i = threadIdx.x; i < nb; i += 256)
            ghist[(size_t)m * NN + base + i] = sh[i];
        return;
    }

    // ---- MFMA GEMM1 ----
    unsigned short* lb = (unsigned short*)sh;  // [s:16][t:2][lane:64][8 bf16] = 32 KB

    // stage W1 -> bf16, pre-swizzled to B-fragment order
    for (int idx = threadIdx.x; idx < 16 * 2 * 64; idx += 256) {
        int s = idx >> 7;
        int rem = idx & 127;
        int t = rem >> 6;
        int l = rem & 63;
        int k0 = s * 32 + (l >> 4) * 8;
        int c = t * 16 + (l & 15);
        bf16x8 w;
#pragma unroll
        for (int i = 0; i < 8; ++i) w[i] = (short)f2bf(W1[(size_t)(k0 + i) * FH + c]);
        *(bf16x8*)(lb + (size_t)idx * 8) = w;
    }
    __syncthreads();

    int wave = threadIdx.x >> 6;
    int lane = threadIdx.x & 63;
    int rowbase = (blockIdx.x - NHB) * 64 + wave * 16;
    int arow = rowbase + (lane & 15);
    int arowc = min(arow, NN - 1);
    int kgrp = (lane >> 4) * 8;

    f32x4 acc0 = {0.f, 0.f, 0.f, 0.f};
    f32x4 acc1 = {0.f, 0.f, 0.f, 0.f};
    const float* xrow = x + (size_t)arowc * FIN + kgrp;

    for (int s = 0; s < 16; ++s) {
        float4 a0 = *(const float4*)(xrow + s * 32);
        float4 a1 = *(const float4*)(xrow + s * 32 + 4);
        bf16x8 af;
        af[0] = (short)f2bf(a0.x); af[1] = (short)f2bf(a0.y);
        af[2] = (short)f2bf(a0.z); af[3] = (short)f2bf(a0.w);
        af[4] = (short)f2bf(a1.x); af[5] = (short)f2bf(a1.y);
        af[6] = (short)f2bf(a1.z); af[7] = (short)f2bf(a1.w);
        bf16x8 b0 = *(const bf16x8*)(lb + ((size_t)(s * 2 + 0) * 64 + lane) * 8);
        bf16x8 b1 = *(const bf16x8*)(lb + ((size_t)(s * 2 + 1) * 64 + lane) * 8);
        acc0 = __builtin_amdgcn_mfma_f32_16x16x32_bf16(af, b0, acc0, 0, 0, 0);
        acc1 = __builtin_amdgcn_mfma_f32_16x16x32_bf16(af, b1, acc1, 0, 0, 0);
    }

    int crow = rowbase + (lane >> 4) * 4;
    int ccol = lane & 15;
#pragma unroll
    for (int r = 0; r < 4; ++r) {
        if (crow + r < NN) {
            h1[(size_t)(crow + r) * FH + ccol] = acc0[r];
            h1[(size_t)(crow + r) * FH + 16 + ccol] = acc1[r];
        }
    }
}

// ---------------- per-node slice-scan: ghist -> block prefixes, cnt, dis ----------------

__global__ __launch_bounds__(SCAN_B) void k_xscan(int* __restrict__ ghist,
                                                  int* __restrict__ cnt,
                                                  float* __restrict__ dis,
                                                  int* __restrict__ part) {
    __shared__ int s[SCAN_B];
    int c = blockIdx.x * SCAN_B + threadIdx.x;
    int sum = 0;
    if (c < NN) {
#pragma unroll 4
        for (int m = 0; m < M_SL; ++m) {
            size_t idx = (size_t)m * NN + c;
            int t = ghist[idx];
            ghist[idx] = sum;  // exclusive prefix (block offset)
            sum += t;
        }
        cnt[c] = sum;
        dis[c] = rsqrtf((float)sum + 1.0f);  // +1 self-loop
    }
    s[threadIdx.x] = sum;
    __syncthreads();
    for (int st = SCAN_B / 2; st > 0; st >>= 1) {
        if (threadIdx.x < st) s[threadIdx.x] += s[threadIdx.x + st];
        __syncthreads();
    }
    if (threadIdx.x == 0) part[blockIdx.x] = s[0];
}

// ---------------- scan of partials ----------------

__global__ __launch_bounds__(128) void k_scanpart(int* __restrict__ part) {
    __shared__ int s[128];
    int t = threadIdx.x;
    int v = (t < NBLK) ? part[t] : 0;
    s[t] = v;
    __syncthreads();
    for (int st = 1; st < 128; st <<= 1) {
        int a = (t >= st) ? s[t - st] : 0;
        __syncthreads();
        s[t] += a;
        __syncthreads();
    }
    if (t < NBLK) part[t] = s[t] - v;  // exclusive
}

__global__ __launch_bounds__(SCAN_B) void k_scanblock(const int* __restrict__ cnt,
                                                      const int* __restrict__ part,
                                                      int* __restrict__ off) {
    __shared__ int s[SCAN_B];
    int i = blockIdx.x * SCAN_B + threadIdx.x;
    int v = (i < NN) ? cnt[i] : 0;
    s[threadIdx.x] = v;
    __syncthreads();
    for (int st = 1; st < SCAN_B; st <<= 1) {
        int add = (threadIdx.x >= st) ? s[threadIdx.x - st] : 0;
        __syncthreads();
        s[threadIdx.x] += add;
        __syncthreads();
    }
    if (i < NN) off[i] = part[blockIdx.x] + s[threadIdx.x] - v;  // exclusive
    if (i == NN - 1) off[NN] = part[blockIdx.x] + s[threadIdx.x];
}

// ---------------- CSR fill: atomic-free, slot = off[c] + ghist[m][c] + rank ----------------

__global__ void k_fill(const int* __restrict__ row, const int* __restrict__ col,
                       const unsigned short* __restrict__ rank,
                       const float* __restrict__ dis, const int* __restrict__ off,
                       const int* __restrict__ ghist, int2* __restrict__ csr) {
    int i = blockIdx.x * blockDim.x + threadIdx.x;  // global quad index
    if (i >= NE / 4) return;
    int m = i / QSL;  // slice
    int4 r4 = ((const int4*)row)[i];
    int4 c4 = ((const int4*)col)[i];
    ushort4 rk4 = ((const ushort4*)rank)[i];
    int rr[4] = {r4.x, r4.y, r4.z, r4.w};
    int cc[4] = {c4.x, c4.y, c4.z, c4.w};
    int rk[4] = {rk4.x, rk4.y, rk4.z, rk4.w};
    float dr[4], dc[4];
    int o4[4], bp[4];
#pragma unroll
    for (int u = 0; u < 4; ++u) dr[u] = dis[rr[u]];
#pragma unroll
    for (int u = 0; u < 4; ++u) dc[u] = dis[cc[u]];
#pragma unroll
    for (int u = 0; u < 4; ++u) o4[u] = off[cc[u]];
#pragma unroll
    for (int u = 0; u < 4; ++u) bp[u] = ghist[(size_t)m * NN + cc[u]];
#pragma unroll
    for (int u = 0; u < 4; ++u)
        csr[o4[u] + bp[u] + rk[u]] = make_int2(rr[u], __float_as_int(dr[u] * dc[u]));
}

// ---------------- gather layer1 + self-loop + bias + relu -> hr ----------------

__global__ __launch_bounds__(256) void k_gather1(const int* __restrict__ off,
                                                 const int2* __restrict__ csr,
                                                 const float* __restrict__ h1,
                                                 const float* __restrict__ dis,
                                                 const float* __restrict__ b1,
                                                 float* __restrict__ hr) {
    int g = blockIdx.x * (256 / FH) + threadIdx.x / FH;
    int f = threadIdx.x & (FH - 1);
    if (g >= NN) return;
    int s0 = off[g], s1 = off[g + 1];
    float acc = 0.0f;
    for (int i = s0; i < s1; ++i) {
        int2 ew = csr[i];
        acc += h1[(size_t)ew.x * FH + f] * __int_as_float(ew.y);
    }
    float d2 = dis[g] * dis[g];
    float v = acc + h1[(size_t)g * FH + f] * d2 + b1[f];
    hr[(size_t)g * FH + f] = v > 0.0f ? v : 0.0f;
}

// ---------------- GEMM2: h2 = hr @ W2 (32 -> 16) ----------------

__global__ __launch_bounds__(256) void k_gemm2(const float* __restrict__ hr,
                                               const float* __restrict__ W2,
                                               float* __restrict__ h2) {
    __shared__ float Wl[FH * FC];  // 2 KB
    for (int i = threadIdx.x; i < FH * FC; i += 256) Wl[i] = W2[i];
    __syncthreads();
    int n = blockIdx.x * blockDim.x + threadIdx.x;
    if (n >= NN) return;
    float h[FH];
    const float4* hp = (const float4*)(hr + (size_t)n * FH);
#pragma unroll
    for (int j = 0; j < FH / 4; ++j) {
        float4 t = hp[j];
        h[4 * j] = t.x; h[4 * j + 1] = t.y; h[4 * j + 2] = t.z; h[4 * j + 3] = t.w;
    }
#pragma unroll
    for (int j = 0; j < FC; ++j) {
        float s = 0.0f;
#pragma unroll
        for (int k = 0; k < FH; ++k) s += h[k] * Wl[k * FC + j];
        h2[(size_t)n * FC + j] = s;
    }
}

// ---------------- gather layer2 + self-loop + bias + log_softmax -> out ----------------

__global__ __launch_bounds__(256) void k_gather2(const int* __restrict__ off,
                                                 const int2* __restrict__ csr,
                                                 const float* __restrict__ h2,
                                                 const float* __restrict__ dis,
                                                 const float* __restrict__ b2,
                                                 float* __restrict__ out) {
    int g = blockIdx.x * (256 / FC) + threadIdx.x / FC;
    int f = threadIdx.x & (FC - 1);
    if (g >= NN) return;
    int s0 = off[g], s1 = off[g + 1];
    float acc = 0.0f;
    for (int i = s0; i < s1; ++i) {
        int2 ew = csr[i];
        acc += h2[(size_t)ew.x * FC + f] * __int_as_float(ew.y);
    }
    float d2 = dis[g] * dis[g];
    float v = acc + h2[(size_t)g * FC + f] * d2 + b2[f];
    float m = v;
#pragma unroll
    for (int o = 1; o < FC; o <<= 1) m = fmaxf(m, __shfl_xor(m, o, FC));
    float e = __expf(v - m);
    float s = e;
#pragma unroll
    for (int o = 1; o < FC; o <<= 1) s += __shfl_xor(s, o, FC);
    out[(size_t)g * FC + f] = v - m - logf(s);
}

extern "C" void kernel_launch(void* const* d_in, const int* in_sizes, int n_in,
                              void* d_out, int out_size, void* d_ws, size_t ws_size,
                              hipStream_t stream) {
    const float* x  = (const float*)d_in[0];
    const int*   ei = (const int*)d_in[1];
    const float* W1 = (const float*)d_in[2];
    const float* b1 = (const float*)d_in[3];
    const float* W2 = (const float*)d_in[4];
    const float* b2 = (const float*)d_in[5];
    float* out = (float*)d_out;

    const int* row = ei;
    const int* col = ei + NE;

    // workspace layout (int units; ~49.2 MB)
    int* base = (int*)d_ws;
    int*   ghist = base;                            // M_SL*NN = 1,600,000
    int*   cnt   = ghist + (size_t)M_SL * NN;       // NN
    int*   off   = cnt + NN;                        // NN+1 (pad to NN+8)
    int*   part  = off + NN + 8;                    // 128
    unsigned short* rank = (unsigned short*)(part + 128);  // NE u16 = 800,000 ints
    float* dis   = (float*)(part + 128 + NE / 2);   // NN
    float* h1    = dis + NN;                        // NN*FH
    float* hr    = h1 + (size_t)NN * FH;            // NN*FH
    int2*  csr   = (int2*)(hr + (size_t)NN * FH);   // NE int2
    float* h2    = h1;                              // reuse: h1 dead after k_gather1

    const int B = 256;

    k_hist_gemm1<<<NHB + NGB1, B, 0, stream>>>(col, ghist, rank, x, W1, h1);
    k_xscan<<<NBLK, SCAN_B, 0, stream>>>(ghist, cnt, dis, part);
    k_scanpart<<<1, 128, 0, stream>>>(part);
    k_scanblock<<<NBLK, SCAN_B, 0, stream>>>(cnt, part, off);
    k_fill<<<NCB, B, 0, stream>>>(row, col, rank, dis, off, ghist, csr);

    k_gather1<<<(NN * FH + B - 1) / B, B, 0, stream>>>(off, csr, h1, dis, b1, hr);
    k_gemm2<<<(NN + B - 1) / B, B, 0, stream>>>(hr, W2, h2);
    k_gather2<<<(NN * FC + B - 1) / B, B, 0, stream>>>(off, csr, h2, dis, b2, out);
}